// Round 4
// baseline (196.401 us; speedup 1.0000x reference)
//
#include <hip/hip_runtime.h>
#include <hip/hip_bf16.h>

#define Bdim 4096
#define Ldim 4096
#define Hdim 1024
#define TILE 128
#define BK 32

typedef __attribute__((ext_vector_type(8))) __bf16 bf16x8;
typedef __attribute__((ext_vector_type(4))) float floatx4;

__device__ __forceinline__ unsigned short f2bf(float f) {
  union { __hip_bfloat16 h; unsigned short u; } c;
  c.h = __float2bfloat16(f);
  return c.u;
}

// ---- fused prep: blocks [0,Ldim) do W->bf16 + bias row; [Ldim, Ldim+Bdim) do X->bf16 row
__global__ __launch_bounds__(256) void prep_kernel(
    const float* __restrict__ X, const float* __restrict__ E,
    const float* __restrict__ W, const float* __restrict__ b,
    unsigned short* __restrict__ Xb, unsigned short* __restrict__ Wb,
    float* __restrict__ bias) {
  const int blk = blockIdx.x;
  const int t = threadIdx.x;
  if (blk < Ldim) {
    const int row = blk;
    const float4 wv = reinterpret_cast<const float4*>(W + (size_t)row * Hdim)[t];
    const float4 ev = reinterpret_cast<const float4*>(E + (size_t)row * Hdim)[t];
    ushort4 o;
    o.x = f2bf(wv.x); o.y = f2bf(wv.y); o.z = f2bf(wv.z); o.w = f2bf(wv.w);
    reinterpret_cast<ushort4*>(Wb + (size_t)row * Hdim)[t] = o;
    float dot = wv.x * ev.x + wv.y * ev.y + wv.z * ev.z + wv.w * ev.w;
#pragma unroll
    for (int off = 32; off > 0; off >>= 1) dot += __shfl_down(dot, off, 64);
    __shared__ float part[4];
    if ((t & 63) == 0) part[t >> 6] = dot;
    __syncthreads();
    if (t == 0) bias[row] = part[0] + part[1] + part[2] + part[3] + b[row];
  } else {
    const int i = (blk - Ldim) * 256 + t;   // float4 index into X
    float4 v = reinterpret_cast<const float4*>(X)[i];
    ushort4 o;
    o.x = f2bf(v.x); o.y = f2bf(v.y); o.z = f2bf(v.z); o.w = f2bf(v.w);
    reinterpret_cast<ushort4*>(Xb)[i] = o;
  }
}

// ---- C[B,L] = Xb @ Wb^T + bias -----------------------------------------
// 128x128 tile, BK=32, 4 waves, each wave 64x64 via 4x4 MFMA 16x16x32 tiles.
// Single-barrier double-buffered pipeline:
//   barrier -> ds_read frags from buf[p] -> issue GLL(kt+1 -> buf[1-p]) -> MFMA
// The end-of-iter barrier's vmcnt drain now lands AFTER a compute phase,
// overlapping the ~300-900cyc global latency instead of stalling on it
// (R1-R3 structure drained with zero overlap). 1 barrier/iter vs 2.
// LDS layout: R1 row-major (row stride 64B); quad-contiguous staging.
// Known 4096 conflict-cycles/block from frag reads — measured neutral (R3).
__global__ __launch_bounds__(256) void gemm_bias_kernel(
    const unsigned short* __restrict__ A,   // [Bdim][Hdim] bf16 bits
    const unsigned short* __restrict__ Bw,  // [Ldim][Hdim] bf16 bits
    const float* __restrict__ bias,         // [Ldim]
    float* __restrict__ C) {                // [Bdim][Ldim] fp32
  __shared__ __align__(16) unsigned short lA[2][TILE * BK];   // 2x8 KB
  __shared__ __align__(16) unsigned short lB[2][TILE * BK];   // 2x8 KB

  const int tid = threadIdx.x;
  const int wave = tid >> 6;
  const int lane = tid & 63;
  const int m_blk = blockIdx.y * TILE;
  const int n_blk = blockIdx.x * TILE;

  // staging: wave stages rows [wave*32, +32). lane -> (row base+lane>>2, kchunk lane&3)
  const int srow = wave * 32 + (lane >> 2);
  const unsigned short* gA = A + (size_t)(m_blk + srow) * Hdim + (lane & 3) * 8;
  const unsigned short* gB = Bw + (size_t)(n_blk + srow) * Hdim + (lane & 3) * 8;
  const int lofs = (wave * 32) * BK;      // wave-uniform LDS base offset (shorts)

  // fragment pointers
  const int wm = (wave >> 1) * 64;
  const int wn = (wave & 1) * 64;
  const int fr = lane & 15;
  const int fq = lane >> 4;
  const int fa = (wm + fr) * BK + fq * 8;   // + mi*16*BK
  const int fb = (wn + fr) * BK + fq * 8;

  floatx4 acc[4][4] = {};

#define GLL(src, dst)                                                  \
  __builtin_amdgcn_global_load_lds(                                    \
      (const __attribute__((address_space(1))) void*)(src),            \
      (__attribute__((address_space(3))) void*)(dst), 16, 0, 0)

#define STAGE(buf)                                                     \
  do {                                                                 \
    GLL(gA, &lA[buf][lofs]);                                           \
    GLL(gA + 16 * Hdim, &lA[buf][lofs + 16 * BK]);                     \
    GLL(gB, &lB[buf][lofs]);                                           \
    GLL(gB + 16 * Hdim, &lB[buf][lofs + 16 * BK]);                     \
    gA += BK;                                                          \
    gB += BK;                                                          \
  } while (0)

#define COMPUTE(buf)                                                   \
  do {                                                                 \
    bf16x8 af[4], bfr[4];                                              \
    _Pragma("unroll")                                                  \
    for (int i = 0; i < 4; ++i) {                                      \
      af[i]  = *reinterpret_cast<const bf16x8*>(&lA[buf][fa + i * 16 * BK]); \
      bfr[i] = *reinterpret_cast<const bf16x8*>(&lB[buf][fb + i * 16 * BK]); \
    }                                                                  \
    _Pragma("unroll")                                                  \
    for (int mi = 0; mi < 4; ++mi)                                     \
      _Pragma("unroll")                                                \
      for (int ni = 0; ni < 4; ++ni)                                   \
        acc[mi][ni] = __builtin_amdgcn_mfma_f32_16x16x32_bf16(         \
            af[mi], bfr[ni], acc[mi][ni], 0, 0, 0);                    \
  } while (0)

  STAGE(0);  // prologue: kt=0 -> buf0

#pragma unroll 1
  for (int kt2 = 0; kt2 < Hdim / BK / 2; ++kt2) {
    // phase A: kt = 2*kt2 in buf0; prefetch kt+1 -> buf1
    __syncthreads();          // drains GLL(2*kt2 -> buf0); prior buf1 reads done
    {
      bf16x8 af[4], bfr[4];
#pragma unroll
      for (int i = 0; i < 4; ++i) {
        af[i]  = *reinterpret_cast<const bf16x8*>(&lA[0][fa + i * 16 * BK]);
        bfr[i] = *reinterpret_cast<const bf16x8*>(&lB[0][fb + i * 16 * BK]);
      }
      STAGE(1);               // issue prefetch; completion enforced at next barrier
#pragma unroll
      for (int mi = 0; mi < 4; ++mi)
#pragma unroll
        for (int ni = 0; ni < 4; ++ni)
          acc[mi][ni] = __builtin_amdgcn_mfma_f32_16x16x32_bf16(
              af[mi], bfr[ni], acc[mi][ni], 0, 0, 0);
    }
    // phase B: kt = 2*kt2+1 in buf1; prefetch kt+2 -> buf0 (unless last)
    __syncthreads();
    {
      bf16x8 af[4], bfr[4];
#pragma unroll
      for (int i = 0; i < 4; ++i) {
        af[i]  = *reinterpret_cast<const bf16x8*>(&lA[1][fa + i * 16 * BK]);
        bfr[i] = *reinterpret_cast<const bf16x8*>(&lB[1][fb + i * 16 * BK]);
      }
      if (kt2 < Hdim / BK / 2 - 1) STAGE(0);
#pragma unroll
      for (int mi = 0; mi < 4; ++mi)
#pragma unroll
        for (int ni = 0; ni < 4; ++ni)
          acc[mi][ni] = __builtin_amdgcn_mfma_f32_16x16x32_bf16(
              af[mi], bfr[ni], acc[mi][ni], 0, 0, 0);
    }
  }
#undef GLL
#undef STAGE
#undef COMPUTE

  // epilogue: C/D layout col=lane&15, row=(lane>>4)*4+reg  [m89-verified]
  const int col0 = n_blk + wn + fr;
  const int row0 = m_blk + wm + fq * 4;
#pragma unroll
  for (int ni = 0; ni < 4; ++ni) {
    const float bs = bias[col0 + ni * 16];
#pragma unroll
    for (int mi = 0; mi < 4; ++mi) {
      float* cp = C + (size_t)(row0 + mi * 16) * Ldim + (col0 + ni * 16);
      floatx4 v = acc[mi][ni];
      cp[0 * (size_t)Ldim] = v.x + bs;
      cp[1 * (size_t)Ldim] = v.y + bs;
      cp[2 * (size_t)Ldim] = v.z + bs;
      cp[3 * (size_t)Ldim] = v.w + bs;
    }
  }
}

extern "C" void kernel_launch(void* const* d_in, const int* in_sizes, int n_in,
                              void* d_out, int out_size, void* d_ws, size_t ws_size,
                              hipStream_t stream) {
  const float* X = (const float*)d_in[0];  // bert_output [B,H]
  const float* E = (const float*)d_in[1];  // label_embed [L,H]
  const float* W = (const float*)d_in[2];  // W [L,H]
  const float* b = (const float*)d_in[3];  // b [L]
  // d_in[4] = labels, unused by the reference output.
  float* out = (float*)d_out;

  unsigned short* Xb = (unsigned short*)d_ws;                 // 8 MB
  unsigned short* Wb = Xb + (size_t)Bdim * Hdim;              // 8 MB
  float* bias = (float*)(Wb + (size_t)Ldim * Hdim);           // 16 KB

  prep_kernel<<<Ldim + Bdim, 256, 0, stream>>>(X, E, W, b, Xb, Wb, bias);
  dim3 grid(Ldim / TILE, Bdim / TILE);
  gemm_bias_kernel<<<grid, 256, 0, stream>>>(Xb, Wb, bias, out);
}

// Round 5
// 192.764 us; speedup vs baseline: 1.0189x; 1.0189x over previous
//
#include <hip/hip_runtime.h>
#include <hip/hip_bf16.h>

#define Bdim 4096
#define Ldim 4096
#define Hdim 1024
#define TILE 128

typedef __attribute__((ext_vector_type(8))) __bf16 bf16x8;
typedef __attribute__((ext_vector_type(4))) float floatx4;

__device__ __forceinline__ unsigned short f2bf(float f) {
  union { __hip_bfloat16 h; unsigned short u; } c;
  c.h = __float2bfloat16(f);
  return c.u;
}

// ---- fused prep -> MFMA-fragment-order bf16 buffers --------------------
// Frag layout: frag[m16][kc][lane][8] shorts, where for source row r, col k:
//   m16 = r>>4, fr = r&15, kc = k>>5, fq = (k>>3)&3, j = k&7, lane = fq*16+fr.
// GEMM then loads a 16x32 fragment with one global_load_dwordx4 at
// base + lane*16B  -> perfectly coalesced, direct to registers, NO LDS.
// blocks [0,Ldim): W row -> Wf (+ bias); [Ldim,Ldim+Bdim): X row -> Xf.
__global__ __launch_bounds__(256) void prep_kernel(
    const float* __restrict__ X, const float* __restrict__ E,
    const float* __restrict__ W, const float* __restrict__ b,
    unsigned short* __restrict__ Xf, unsigned short* __restrict__ Wf,
    float* __restrict__ bias) {
  const int blk = blockIdx.x;
  const int t = threadIdx.x;          // k0 = 4t
  const int kc = t >> 3;              // 32-col chunk
  const int fq = (t >> 1) & 3;        // 8-col quad within chunk
  const int j = (t & 1) * 4;          // element offset within quad
  const bool isW = blk < Ldim;
  const int row = isW ? blk : blk - Ldim;
  const int m16 = row >> 4;
  const int fr = row & 15;
  const size_t dofs = ((size_t)(m16 * 32 + kc) * 64 + fq * 16 + fr) * 8 + j;
  if (isW) {
    const float4 wv = reinterpret_cast<const float4*>(W + (size_t)row * Hdim)[t];
    const float4 ev = reinterpret_cast<const float4*>(E + (size_t)row * Hdim)[t];
    ushort4 o;
    o.x = f2bf(wv.x); o.y = f2bf(wv.y); o.z = f2bf(wv.z); o.w = f2bf(wv.w);
    *reinterpret_cast<ushort4*>(Wf + dofs) = o;
    float dot = wv.x * ev.x + wv.y * ev.y + wv.z * ev.z + wv.w * ev.w;
#pragma unroll
    for (int off = 32; off > 0; off >>= 1) dot += __shfl_down(dot, off, 64);
    __shared__ float part[4];
    if ((t & 63) == 0) part[t >> 6] = dot;
    __syncthreads();
    if (t == 0) bias[row] = part[0] + part[1] + part[2] + part[3] + b[row];
  } else {
    const float4 xv = reinterpret_cast<const float4*>(X + (size_t)row * Hdim)[t];
    ushort4 o;
    o.x = f2bf(xv.x); o.y = f2bf(xv.y); o.z = f2bf(xv.z); o.w = f2bf(xv.w);
    *reinterpret_cast<ushort4*>(Xf + dofs) = o;
  }
}

// ---- C[B,L] = X @ W^T + bias, fragment-streaming, no LDS, no barriers --
// 128x128 block tile, 4 waves, wave tile 64x64 (4x4 MFMA 16x16x32).
// All fragments loaded straight from the pre-swizzled global buffers with
// coalesced dwordx4 (1KB/wave-inst). Manual 1-deep register double-buffer:
// issue kc+1's 8 loads, then run kc's 16 MFMAs -> compiler emits
// fine-grained vmcnt waits (no barrier forces vmcnt(0) drains).
__global__ __launch_bounds__(256, 3) void gemm_bias_kernel(
    const unsigned short* __restrict__ Af,  // [Bdim/16][32][64][8]
    const unsigned short* __restrict__ Bf,  // [Ldim/16][32][64][8]
    const float* __restrict__ bias,         // [Ldim]
    float* __restrict__ C) {                // [Bdim][Ldim] fp32
  const int tid = threadIdx.x;
  const int wave = tid >> 6;
  const int lane = tid & 63;
  const int m_blk = blockIdx.y * TILE;
  const int n_blk = blockIdx.x * TILE;
  const int wm = (wave >> 1) * 64;
  const int wn = (wave & 1) * 64;

  // fragment stream pointers: m16 stride = 32*512 shorts, kc stride = 512
  const unsigned short* pa =
      Af + (size_t)((m_blk + wm) >> 4) * 32 * 512 + lane * 8;
  const unsigned short* pb =
      Bf + (size_t)((n_blk + wn) >> 4) * 32 * 512 + lane * 8;

  floatx4 acc[4][4] = {};

  bf16x8 a0[4], b0[4], a1[4], b1[4];
#pragma unroll
  for (int i = 0; i < 4; ++i) {
    a0[i] = *reinterpret_cast<const bf16x8*>(pa + i * 16384);
    b0[i] = *reinterpret_cast<const bf16x8*>(pb + i * 16384);
  }

#pragma unroll 1
  for (int kc = 0; kc < 32; kc += 2) {
    // prefetch kc+1 into buf1
#pragma unroll
    for (int i = 0; i < 4; ++i) {
      a1[i] = *reinterpret_cast<const bf16x8*>(pa + i * 16384 + (kc + 1) * 512);
      b1[i] = *reinterpret_cast<const bf16x8*>(pb + i * 16384 + (kc + 1) * 512);
    }
#pragma unroll
    for (int mi = 0; mi < 4; ++mi)
#pragma unroll
      for (int ni = 0; ni < 4; ++ni)
        acc[mi][ni] = __builtin_amdgcn_mfma_f32_16x16x32_bf16(
            a0[mi], b0[ni], acc[mi][ni], 0, 0, 0);
    // prefetch kc+2 into buf0 (reads past-end guarded by kc<30 check)
    if (kc < 30) {
#pragma unroll
      for (int i = 0; i < 4; ++i) {
        a0[i] = *reinterpret_cast<const bf16x8*>(pa + i * 16384 + (kc + 2) * 512);
        b0[i] = *reinterpret_cast<const bf16x8*>(pb + i * 16384 + (kc + 2) * 512);
      }
    }
#pragma unroll
    for (int mi = 0; mi < 4; ++mi)
#pragma unroll
      for (int ni = 0; ni < 4; ++ni)
        acc[mi][ni] = __builtin_amdgcn_mfma_f32_16x16x32_bf16(
            a1[mi], b1[ni], acc[mi][ni], 0, 0, 0);
  }

  // epilogue: C/D layout col=lane&15, row=(lane>>4)*4+reg  [m89-verified]
  const int fr = lane & 15;
  const int fq = lane >> 4;
  const int col0 = n_blk + wn + fr;
  const int row0 = m_blk + wm + fq * 4;
#pragma unroll
  for (int ni = 0; ni < 4; ++ni) {
    const float bs = bias[col0 + ni * 16];
#pragma unroll
    for (int mi = 0; mi < 4; ++mi) {
      float* cp = C + (size_t)(row0 + mi * 16) * Ldim + (col0 + ni * 16);
      floatx4 v = acc[mi][ni];
      cp[0 * (size_t)Ldim] = v.x + bs;
      cp[1 * (size_t)Ldim] = v.y + bs;
      cp[2 * (size_t)Ldim] = v.z + bs;
      cp[3 * (size_t)Ldim] = v.w + bs;
    }
  }
}

extern "C" void kernel_launch(void* const* d_in, const int* in_sizes, int n_in,
                              void* d_out, int out_size, void* d_ws, size_t ws_size,
                              hipStream_t stream) {
  const float* X = (const float*)d_in[0];  // bert_output [B,H]
  const float* E = (const float*)d_in[1];  // label_embed [L,H]
  const float* W = (const float*)d_in[2];  // W [L,H]
  const float* b = (const float*)d_in[3];  // b [L]
  // d_in[4] = labels, unused by the reference output.
  float* out = (float*)d_out;

  unsigned short* Xf = (unsigned short*)d_ws;                 // 8 MB
  unsigned short* Wf = Xf + (size_t)Bdim * Hdim;              // 8 MB
  float* bias = (float*)(Wf + (size_t)Ldim * Hdim);           // 16 KB

  prep_kernel<<<Ldim + Bdim, 256, 0, stream>>>(X, E, W, b, Xf, Wf, bias);
  dim3 grid(Ldim / TILE, Bdim / TILE);
  gemm_bias_kernel<<<grid, 256, 0, stream>>>(Xf, Wf, bias, out);
}

// Round 6
// 185.234 us; speedup vs baseline: 1.0603x; 1.0407x over previous
//
#include <hip/hip_runtime.h>
#include <hip/hip_bf16.h>

#define Bdim 4096
#define Ldim 4096
#define Hdim 1024
#define TILE 128
#define BK 32

typedef __attribute__((ext_vector_type(8))) __bf16 bf16x8;
typedef __attribute__((ext_vector_type(4))) float floatx4;

__device__ __forceinline__ unsigned short f2bf(float f) {
  union { __hip_bfloat16 h; unsigned short u; } c;
  c.h = __float2bfloat16(f);
  return c.u;
}

// ---- fused prep: blocks [0,Ldim) do W->bf16 + bias row; [Ldim,+Bdim) X->bf16
__global__ __launch_bounds__(256) void prep_kernel(
    const float* __restrict__ X, const float* __restrict__ E,
    const float* __restrict__ W, const float* __restrict__ b,
    unsigned short* __restrict__ Xb, unsigned short* __restrict__ Wb,
    float* __restrict__ bias) {
  const int blk = blockIdx.x;
  const int t = threadIdx.x;
  if (blk < Ldim) {
    const int row = blk;
    const float4 wv = reinterpret_cast<const float4*>(W + (size_t)row * Hdim)[t];
    const float4 ev = reinterpret_cast<const float4*>(E + (size_t)row * Hdim)[t];
    ushort4 o;
    o.x = f2bf(wv.x); o.y = f2bf(wv.y); o.z = f2bf(wv.z); o.w = f2bf(wv.w);
    reinterpret_cast<ushort4*>(Wb + (size_t)row * Hdim)[t] = o;
    float dot = wv.x * ev.x + wv.y * ev.y + wv.z * ev.z + wv.w * ev.w;
#pragma unroll
    for (int off = 32; off > 0; off >>= 1) dot += __shfl_down(dot, off, 64);
    __shared__ float part[4];
    if ((t & 63) == 0) part[t >> 6] = dot;
    __syncthreads();
    if (t == 0) bias[row] = part[0] + part[1] + part[2] + part[3] + b[row];
  } else {
    const int i = (blk - Ldim) * 256 + t;
    float4 v = reinterpret_cast<const float4*>(X)[i];
    ushort4 o;
    o.x = f2bf(v.x); o.y = f2bf(v.y); o.z = f2bf(v.z); o.w = f2bf(v.w);
    reinterpret_cast<ushort4*>(Xb)[i] = o;
  }
}

// ---- C[B,L] = Xb @ Wb^T + bias -----------------------------------------
// 128x128 tile, BK=32, 4 waves (64x64 each, 4x4 MFMA 16x16x32).
// AITER-style K-loop: LDS ring depth 3, raw s_barrier with fine-grained
// s_waitcnt vmcnt(4) -- the NEXT stage's 4 GLLs stay in flight across the
// barrier (vs __syncthreads' vmcnt(0) drain, the R1-R4 stall).
// Per iter: wait own stage-kt GLLs (vmcnt<=4) -> s_barrier -> issue stage
// kt+2 into slot (kt+2)%3 (safe: all waves past barrier => done reading
// slot (kt-1)%3) -> ds_read frags of slot kt%3 -> 16 MFMAs.
__global__ __launch_bounds__(256) void gemm_bias_kernel(
    const unsigned short* __restrict__ A,   // [Bdim][Hdim] bf16 bits
    const unsigned short* __restrict__ Bw,  // [Ldim][Hdim] bf16 bits
    const float* __restrict__ bias,         // [Ldim]
    float* __restrict__ C) {                // [Bdim][Ldim] fp32
  __shared__ __align__(16) unsigned short ring[3][2][TILE * BK];  // 48 KB

  const int tid = threadIdx.x;
  const int wave = tid >> 6;
  const int lane = tid & 63;
  const int m_blk = blockIdx.y * TILE;
  const int n_blk = blockIdx.x * TILE;

  // staging: wave stages rows [wave*32,+32); lane -> (row +lane>>2, kchunk lane&3)
  const int srow = wave * 32 + (lane >> 2);
  const unsigned short* gA = A + (size_t)(m_blk + srow) * Hdim + (lane & 3) * 8;
  const unsigned short* gB = Bw + (size_t)(n_blk + srow) * Hdim + (lane & 3) * 8;
  const int lofs = wave * 32 * BK;   // wave-uniform LDS offset (shorts)

  // fragment read offsets (R1 row-major layout; 4096 conflict-cyc/block = neutral per R3)
  const int wm = (wave >> 1) * 64;
  const int wn = (wave & 1) * 64;
  const int fr = lane & 15;
  const int fq = lane >> 4;
  const int fa = (wm + fr) * BK + fq * 8;   // + mi*16*BK
  const int fb = (wn + fr) * BK + fq * 8;

  floatx4 acc[4][4] = {};

#define GLL(src, dst)                                                  \
  __builtin_amdgcn_global_load_lds(                                    \
      (const __attribute__((address_space(1))) void*)(src),            \
      (__attribute__((address_space(3))) void*)(dst), 16, 0, 0)

#define STAGE(slot, kk)                                                \
  do {                                                                 \
    GLL(gA + (kk) * BK, &ring[slot][0][lofs]);                         \
    GLL(gA + (kk) * BK + 16 * Hdim, &ring[slot][0][lofs + 16 * BK]);   \
    GLL(gB + (kk) * BK, &ring[slot][1][lofs]);                         \
    GLL(gB + (kk) * BK + 16 * Hdim, &ring[slot][1][lofs + 16 * BK]);   \
  } while (0)

#define COMPUTE(slot)                                                  \
  do {                                                                 \
    bf16x8 af[4], bfr[4];                                              \
    _Pragma("unroll")                                                  \
    for (int i = 0; i < 4; ++i) {                                      \
      af[i]  = *reinterpret_cast<const bf16x8*>(&ring[slot][0][fa + i * 16 * BK]); \
      bfr[i] = *reinterpret_cast<const bf16x8*>(&ring[slot][1][fb + i * 16 * BK]); \
    }                                                                  \
    _Pragma("unroll")                                                  \
    for (int mi = 0; mi < 4; ++mi)                                     \
      _Pragma("unroll")                                                \
      for (int ni = 0; ni < 4; ++ni)                                   \
        acc[mi][ni] = __builtin_amdgcn_mfma_f32_16x16x32_bf16(         \
            af[mi], bfr[ni], acc[mi][ni], 0, 0, 0);                    \
  } while (0)

#define WAIT4_BAR asm volatile("s_waitcnt vmcnt(4)\n\ts_barrier" ::: "memory")
#define WAIT0_BAR asm volatile("s_waitcnt vmcnt(0)\n\ts_barrier" ::: "memory")

  STAGE(0, 0);   // 4 GLLs in flight
  STAGE(1, 1);   // 8 in flight

#pragma unroll 1
  for (int kt = 0; kt < 30; kt += 3) {
    WAIT4_BAR;            // stage kt done; kt+1 in flight
    STAGE(2, kt + 2);     // 8 in flight
    COMPUTE(0);           // k-step kt
    WAIT4_BAR;            // stage kt+1 done; kt+2 in flight
    STAGE(0, kt + 3);
    COMPUTE(1);           // k-step kt+1
    WAIT4_BAR;            // stage kt+2 done; kt+3 in flight
    STAGE(1, kt + 4);
    COMPUTE(2);           // k-step kt+2
  }
  // staged so far: ..., 30 -> slot0, 31 -> slot1; in flight: 30,31
  WAIT4_BAR;              // stage 30 done; 31 in flight
  COMPUTE(0);             // k-step 30
  WAIT0_BAR;              // stage 31 done
  COMPUTE(1);             // k-step 31

#undef GLL
#undef STAGE
#undef COMPUTE
#undef WAIT4_BAR
#undef WAIT0_BAR

  // epilogue: C/D layout col=lane&15, row=(lane>>4)*4+reg  [m89-verified]
  const int col0 = n_blk + wn + fr;
  const int row0 = m_blk + wm + fq * 4;
#pragma unroll
  for (int ni = 0; ni < 4; ++ni) {
    const float bs = bias[col0 + ni * 16];
#pragma unroll
    for (int mi = 0; mi < 4; ++mi) {
      float* cp = C + (size_t)(row0 + mi * 16) * Ldim + (col0 + ni * 16);
      floatx4 v = acc[mi][ni];
      cp[0 * (size_t)Ldim] = v.x + bs;
      cp[1 * (size_t)Ldim] = v.y + bs;
      cp[2 * (size_t)Ldim] = v.z + bs;
      cp[3 * (size_t)Ldim] = v.w + bs;
    }
  }
}

extern "C" void kernel_launch(void* const* d_in, const int* in_sizes, int n_in,
                              void* d_out, int out_size, void* d_ws, size_t ws_size,
                              hipStream_t stream) {
  const float* X = (const float*)d_in[0];  // bert_output [B,H]
  const float* E = (const float*)d_in[1];  // label_embed [L,H]
  const float* W = (const float*)d_in[2];  // W [L,H]
  const float* b = (const float*)d_in[3];  // b [L]
  // d_in[4] = labels, unused by the reference output.
  float* out = (float*)d_out;

  unsigned short* Xb = (unsigned short*)d_ws;                 // 8 MB
  unsigned short* Wb = Xb + (size_t)Bdim * Hdim;              // 8 MB
  float* bias = (float*)(Wb + (size_t)Ldim * Hdim);           // 16 KB

  prep_kernel<<<Ldim + Bdim, 256, 0, stream>>>(X, E, W, b, Xb, Wb, bias);
  dim3 grid(Ldim / TILE, Bdim / TILE);
  gemm_bias_kernel<<<grid, 256, 0, stream>>>(Xb, Wb, bias, out);
}